// Round 1
// baseline (211.441 us; speedup 1.0000x reference)
//
#include <hip/hip_runtime.h>

// Chamfer loss: predict_pc [B=4, 3, N=8192] f32, gt_pc [B, 3, N] f32.
// loss = sum_gt min_pred d / B + sum_pred min_gt d / B
// Strategy: min(sqrt(d2)) = sqrt(min(d2)); compute squared distances only.
// Per-direction kernel: thread owns QPT query points (registers), opposite
// points staged in LDS (float4, broadcast reads). Opposite dim chunked for
// parallelism; partial mins merged with int atomicMin (exact & deterministic
// for non-negative floats). Final single-block reduction: sqrt + sum + /B.

#define BQ 256          // threads per block
#define QPT 4           // query points per thread
#define QTILE (BQ*QPT)  // 1024 queries per block
#define GCHUNK 1024     // opposite points staged per block

__global__ __launch_bounds__(BQ) void chamfer_min_kernel(
    const float* __restrict__ qpts,   // [B,3,N] query side (min is FOR these)
    const float* __restrict__ opts,   // [B,3,N] opposite side (min is OVER these)
    int* __restrict__ minbuf,         // [B,N] f32-as-int running min of d2
    int N, int qtiles, int gchunks)
{
    int bid = blockIdx.x;
    int gc = bid % gchunks;
    int qt = (bid / gchunks) % qtiles;
    int b  = bid / (gchunks * qtiles);

    __shared__ float4 lds[GCHUNK];

    const float* qb = qpts + (size_t)b * 3 * N;
    const float* ob = opts + (size_t)b * 3 * N;

    // stage opposite chunk into LDS (coalesced per-component global reads)
    int gbase = gc * GCHUNK;
    for (int i = threadIdx.x; i < GCHUNK; i += BQ) {
        int gi = gbase + i;
        lds[i] = make_float4(ob[gi], ob[N + gi], ob[2 * N + gi], 0.0f);
    }
    __syncthreads();

    // load query points into registers
    float px[QPT], py[QPT], pz[QPT], mn[QPT];
    int q0 = qt * QTILE + threadIdx.x;
    #pragma unroll
    for (int q = 0; q < QPT; ++q) {
        int qi = q0 + q * BQ;
        px[q] = qb[qi];
        py[q] = qb[N + qi];
        pz[q] = qb[2 * N + qi];
        mn[q] = 3.0e38f;
    }

    // main loop: uniform LDS address per iteration -> broadcast (no conflicts)
    #pragma unroll 4
    for (int j = 0; j < GCHUNK; ++j) {
        float4 g = lds[j];
        #pragma unroll
        for (int q = 0; q < QPT; ++q) {
            float dx = px[q] - g.x;
            float dy = py[q] - g.y;
            float dz = pz[q] - g.z;
            float d2 = fmaf(dx, dx, fmaf(dy, dy, dz * dz));
            mn[q] = fminf(mn[q], d2);
        }
    }

    // merge partial mins: non-negative f32 bit patterns order like signed ints
    int* mb = minbuf + b * N;
    #pragma unroll
    for (int q = 0; q < QPT; ++q) {
        atomicMin(mb + q0 + q * BQ, __float_as_int(mn[q]));
    }
}

__global__ __launch_bounds__(256) void chamfer_reduce_kernel(
    const int* __restrict__ minbuf, float* __restrict__ out,
    int total, float inv_b)
{
    __shared__ float sdata[256];
    float s = 0.0f;
    for (int i = threadIdx.x; i < total; i += 256) {
        float d2 = __int_as_float(minbuf[i]);
        s += sqrtf(fmaxf(d2, 0.0f));
    }
    sdata[threadIdx.x] = s;
    __syncthreads();
    for (int off = 128; off > 0; off >>= 1) {
        if (threadIdx.x < off) sdata[threadIdx.x] += sdata[threadIdx.x + off];
        __syncthreads();
    }
    if (threadIdx.x == 0) out[0] = sdata[0] * inv_b;
}

extern "C" void kernel_launch(void* const* d_in, const int* in_sizes, int n_in,
                              void* d_out, int out_size, void* d_ws, size_t ws_size,
                              hipStream_t stream) {
    const float* pred = (const float*)d_in[0];
    const float* gt   = (const float*)d_in[1];
    const int B = 4, D = 3;
    const int N = in_sizes[0] / (B * D);   // 8192

    int* minbuf = (int*)d_ws;              // 2*B*N ints = 256 KB
    size_t mb_bytes = (size_t)2 * B * N * sizeof(int);
    // 0x7F7F7F7F as float = 3.39e38 (positive) -> works as +inf sentinel
    hipMemsetAsync(d_ws, 0x7F, mb_bytes, stream);

    int qtiles  = N / QTILE;   // 8
    int gchunks = N / GCHUNK;  // 8
    dim3 grid(B * qtiles * gchunks), block(BQ);

    // z: for each gt point, min over pred  -> queries = gt, opposite = pred
    chamfer_min_kernel<<<grid, block, 0, stream>>>(gt, pred, minbuf, N, qtiles, gchunks);
    // z2: for each pred point, min over gt -> queries = pred, opposite = gt
    chamfer_min_kernel<<<grid, block, 0, stream>>>(pred, gt, minbuf + B * N, N, qtiles, gchunks);

    chamfer_reduce_kernel<<<1, 256, 0, stream>>>(minbuf, (float*)d_out,
                                                 2 * B * N, 1.0f / B);
}

// Round 2
// 56.878 us; speedup vs baseline: 3.7174x; 3.7174x over previous
//
#include <hip/hip_runtime.h>

// Chamfer loss: predict_pc [B=4, 3, N=8192] f32, gt_pc [B, 3, N] f32.
// loss = sum_gt min_pred d / B + sum_pred min_gt d / B
//
// Algebra: d2 = |p|^2 + |g|^2 - 2 p.g  (the reference's own decomposition).
// For fixed query p:  min_g d2 = |p|^2 - 2 * max_g s,  s = p.g - 0.5|g|^2.
// Stage opposite points in LDS as (gx,gy,gz, -0.5|g|^2); inner loop is
// 3 FMA + 1 max per pair. min(sqrt(x)) = sqrt(min(x)) -> sqrt only at end.
// Partial maxes -> d2 -> global int atomicMin (exact, order-independent on
// non-negative floats => deterministic). Two-stage tree reduction for the sum.

#define BQ 256          // threads per block
#define QPT 4           // query points per thread (4 independent dep-chains)
#define QTILE (BQ*QPT)  // 1024 queries per block
#define GCHUNK 512      // opposite points staged per block
#define RBLKS 64        // stage-1 reduction blocks

__global__ __launch_bounds__(BQ) void chamfer_min_kernel(
    const float* __restrict__ pred, const float* __restrict__ gt,
    int* __restrict__ minbuf,       // [2,B,N] f32-as-int running min of d2
    int N, int qtiles, int gchunks, int n_per_dir)
{
    int bid = blockIdx.x;
    int dir = bid / n_per_dir;          // 0: queries=gt, min over pred (z)
    int r   = bid - dir * n_per_dir;    // 1: queries=pred, min over gt (z2)
    int gc  = r % gchunks;
    int qt  = (r / gchunks) % qtiles;
    int b   = r / (gchunks * qtiles);

    const float* qpts = dir ? pred : gt;
    const float* opts = dir ? gt   : pred;
    int* mb = minbuf + (size_t)dir * 4 * N + (size_t)b * N;

    const float* qb = qpts + (size_t)b * 3 * N;
    const float* ob = opts + (size_t)b * 3 * N;

    __shared__ float4 lds[GCHUNK];

    // stage opposite chunk: (gx, gy, gz, -0.5*|g|^2)
    int gbase = gc * GCHUNK;
    for (int i = threadIdx.x; i < GCHUNK; i += BQ) {
        int gi = gbase + i;
        float gx = ob[gi], gy = ob[N + gi], gz = ob[2 * N + gi];
        float w = -0.5f * fmaf(gx, gx, fmaf(gy, gy, gz * gz));
        lds[i] = make_float4(gx, gy, gz, w);
    }
    __syncthreads();

    // query points in registers
    float px[QPT], py[QPT], pz[QPT], qn[QPT], mx[QPT];
    int q0 = qt * QTILE + threadIdx.x;
    #pragma unroll
    for (int q = 0; q < QPT; ++q) {
        int qi = q0 + q * BQ;
        px[q] = qb[qi];
        py[q] = qb[N + qi];
        pz[q] = qb[2 * N + qi];
        qn[q] = fmaf(px[q], px[q], fmaf(py[q], py[q], pz[q] * pz[q]));
        mx[q] = -3.0e38f;
    }

    // main loop: uniform LDS address -> broadcast, no bank conflicts
    #pragma unroll 8
    for (int j = 0; j < GCHUNK; ++j) {
        float4 g = lds[j];
        #pragma unroll
        for (int q = 0; q < QPT; ++q) {
            float s = fmaf(px[q], g.x, fmaf(py[q], g.y, fmaf(pz[q], g.z, g.w)));
            mx[q] = fmaxf(mx[q], s);
        }
    }

    // d2 = qn - 2*mx >= 0 (clamped); int-min on non-negative floats is exact
    #pragma unroll
    for (int q = 0; q < QPT; ++q) {
        float d2 = fmaxf(fmaf(-2.0f, mx[q], qn[q]), 0.0f);
        atomicMin(mb + q0 + q * BQ, __float_as_int(d2));
    }
}

__global__ __launch_bounds__(256) void chamfer_reduce1_kernel(
    const int* __restrict__ minbuf, float* __restrict__ partials, int per_blk)
{
    __shared__ float sdata[256];
    int base = blockIdx.x * per_blk + threadIdx.x;
    float s = 0.0f;
    for (int k = 0; k < per_blk; k += 256) {
        float d2 = __int_as_float(minbuf[base + k]);
        s += sqrtf(fmaxf(d2, 0.0f));
    }
    sdata[threadIdx.x] = s;
    __syncthreads();
    for (int off = 128; off > 0; off >>= 1) {
        if (threadIdx.x < off) sdata[threadIdx.x] += sdata[threadIdx.x + off];
        __syncthreads();
    }
    if (threadIdx.x == 0) partials[blockIdx.x] = sdata[0];
}

__global__ __launch_bounds__(64) void chamfer_reduce2_kernel(
    const float* __restrict__ partials, float* __restrict__ out, float inv_b)
{
    __shared__ float sdata[64];
    sdata[threadIdx.x] = partials[threadIdx.x];
    __syncthreads();
    for (int off = 32; off > 0; off >>= 1) {
        if (threadIdx.x < off) sdata[threadIdx.x] += sdata[threadIdx.x + off];
        __syncthreads();
    }
    if (threadIdx.x == 0) out[0] = sdata[0] * inv_b;
}

extern "C" void kernel_launch(void* const* d_in, const int* in_sizes, int n_in,
                              void* d_out, int out_size, void* d_ws, size_t ws_size,
                              hipStream_t stream) {
    const float* pred = (const float*)d_in[0];
    const float* gt   = (const float*)d_in[1];
    const int B = 4, D = 3;
    const int N = in_sizes[0] / (B * D);   // 8192
    const int total = 2 * B * N;           // 65536

    int* minbuf = (int*)d_ws;                          // 256 KB
    float* partials = (float*)((char*)d_ws + (size_t)total * sizeof(int));
    // 0x7F7F7F7F as float = 3.39e38 (positive) -> +inf sentinel
    hipMemsetAsync(d_ws, 0x7F, (size_t)total * sizeof(int), stream);

    int qtiles  = N / QTILE;    // 8
    int gchunks = N / GCHUNK;   // 16
    int n_per_dir = B * qtiles * gchunks;  // 512
    chamfer_min_kernel<<<dim3(2 * n_per_dir), dim3(BQ), 0, stream>>>(
        pred, gt, minbuf, N, qtiles, gchunks, n_per_dir);

    chamfer_reduce1_kernel<<<dim3(RBLKS), dim3(256), 0, stream>>>(
        minbuf, partials, total / RBLKS);
    chamfer_reduce2_kernel<<<dim3(1), dim3(64), 0, stream>>>(
        partials, (float*)d_out, 1.0f / B);
}